// Round 6
// baseline (194961.987 us; speedup 1.0000x reference)
//
#include <hip/hip_runtime.h>

// WaveNet autoregressive generator, MI355X. Inputs fp32, OUTPUT fp32.
// Round 6: identical to round-5 monolith except d_out is float (the reference
// output dtype is float32; bf16 writes were the sole failure cause per the
// identical-6.5 evidence). 4 blocks (one per batch, independent) x 256
// threads; 800-step recurrence inside one block, __syncthreads only. State
// math in fp64; weights f32 streamed from L2/LLC. Dilated past terms via
// per-layer res-history rings in d_ws.

typedef unsigned long long u64;

#define TSTEPS 800
#define CREP 200
#define ZB_OFF 0            // f64 zb[b][l][e][256] : 4*16*4*256*8 = 524288 B
#define RING_OFF 524288     // f32 ring[b][510*128] : 4*510*128*4 = 1044480 B

__global__ __launch_bounds__(256, 1) void wn_mono(
    const float* __restrict__ enc, const float* __restrict__ Wfirst,
    const float* __restrict__ bfirst, const float* __restrict__ Wc,
    const float* __restrict__ bcv, const float* __restrict__ Wcond,
    const float* __restrict__ Wres, const float* __restrict__ bres,
    const float* __restrict__ Wskip, const float* __restrict__ bskipl,
    const float* __restrict__ Wskip0, const float* __restrict__ bskip0,
    const float* __restrict__ Wct, const float* __restrict__ Wfcw,
    const float* __restrict__ bfc, const float* __restrict__ Wlg,
    const float* __restrict__ blgg, float* __restrict__ dout,
    unsigned char* __restrict__ ws) {
  __shared__ double resL[128], hL[128], skipL[128], s1L[128], tmpL[128];
  __shared__ double zL[256], partA[256], partB[256];
  __shared__ double ct2L[512], encL[256];
  __shared__ double amaxv[4];
  __shared__ int amaxi[4];
  __shared__ int argix[1];

  const int tid = threadIdx.x;
  const int b = blockIdx.x;
  const int j2 = tid & 127, kh = tid >> 7;
  const int lane = tid & 63, w = tid >> 6;

  double* zbw = (double*)(ws + ZB_OFF) + (size_t)b * (16 * 4 * 256);
  float* ringb = (float*)(ws + RING_OFF) + (size_t)b * (510 * 128);

  // zero this batch's ring (queues start at zero; ws is poisoned each launch)
  for (int i = tid; i < 510 * 128; i += 256) ringb[i] = 0.f;
  // stage encodings: encL[e*64+c] = enc[b][c][e]
  {
    const int e = tid >> 6, c = tid & 63;
    encL[tid] = (double)enc[(b * 64 + c) * 4 + e];
  }
  __syncthreads();

  // zb[l][e][j] = bc[l][j] + c_e(b) @ Wcond[l][j][:]
  for (int l = 0; l < 16; l++) {
    const float* wrow = Wcond + ((size_t)l * 256 + tid) * 64;
    double a0 = (double)bcv[l * 256 + tid];
    double a1 = a0, a2 = a0, a3 = a0;
    for (int c = 0; c < 64; c++) {
      const double wv = (double)wrow[c];
      a0 += encL[c] * wv;
      a1 += encL[64 + c] * wv;
      a2 += encL[128 + c] * wv;
      a3 += encL[192 + c] * wv;
    }
    zbw[(l * 4 + 0) * 256 + tid] = a0;
    zbw[(l * 4 + 1) * 256 + tid] = a1;
    zbw[(l * 4 + 2) * 256 + tid] = a2;
    zbw[(l * 4 + 3) * 256 + tid] = a3;
  }
  // ct2[e][s] = c_e(b) @ Wcond_top[s][:]
  if (tid < 128) {
    const float* wrow = Wct + (size_t)tid * 64;
    double a0 = 0, a1 = 0, a2 = 0, a3 = 0;
    for (int c = 0; c < 64; c++) {
      const double wv = (double)wrow[c];
      a0 += encL[c] * wv;
      a1 += encL[64 + c] * wv;
      a2 += encL[128 + c] * wv;
      a3 += encL[192 + c] * wv;
    }
    ct2L[0 * 128 + tid] = a0;
    ct2L[1 * 128 + tid] = a1;
    ct2L[2 * 128 + tid] = a2;
    ct2L[3 * 128 + tid] = a3;
  }

  double bs0sum = 0.0, wf0 = 0.0, wf1 = 0.0, bfv = 0.0, bfcv = 0.0;
  if (tid < 128) {
    bs0sum = (double)bskip0[j2];
    for (int l = 0; l < 16; l++) bs0sum += (double)bskipl[l * 128 + j2];
    wf0 = (double)Wfirst[2 * j2];
    wf1 = (double)Wfirst[2 * j2 + 1];
    bfv = (double)bfirst[j2];
    bfcv = (double)bfc[j2];
  }
  const double blgv = (double)blgg[tid];
  double fq = 0.0;
  double x = (double)(128.f / 127.5f - 1.f);  // mimic reference f32 rounding
  __syncthreads();

  for (int t = 0; t < TSTEPS; t++) {
    const int e = t / CREP;

    // first causal conv (k=2): res0 = fq*W0 + x*W1 + b
    if (tid < 128) resL[j2] = fq * wf0 + x * wf1 + bfv;
    __syncthreads();

    // skip = res0 @ Wskip0.T + (bskip0 + sum_l bskip_l)
    {
      const float4* wr = (const float4*)(Wskip0 + (size_t)j2 * 128 + kh * 64);
      double p = 0.0;
      for (int k4 = 0; k4 < 16; k4++) {
        const float4 v = wr[k4];
        const int bb = kh * 64 + 4 * k4;
        p += resL[bb] * (double)v.x + resL[bb + 1] * (double)v.y +
             resL[bb + 2] * (double)v.z + resL[bb + 3] * (double)v.w;
      }
      partA[tid] = p;
    }
    __syncthreads();
    if (tid < 128) skipL[j2] = bs0sum + partA[j2] + partA[j2 + 128];
    __syncthreads();

    // 16 dilated gated layers
    int pfx = 0;
    for (int l = 0; l < 16; l++) {
      const int dl = 1 << (l & 7);
      float* ringslot = ringb + pfx * 128 + (t % dl) * 128;  // holds res_l(t-dl)

      // z_j = past@Wc0[j] + res@Wc1[j] + zb[l][e][j]
      {
        const float4* wrow = (const float4*)(Wc + ((size_t)(l * 256 + tid)) * 256);
        double acc = zbw[(l * 4 + e) * 256 + tid];
        for (int k4 = 0; k4 < 64; k4++) {
          const float4 v = wrow[k4];  // {k0.tap0, k0.tap1, k1.tap0, k1.tap1}
          const int k0 = 2 * k4, k1 = 2 * k4 + 1;
          acc += (double)ringslot[k0] * (double)v.x + resL[k0] * (double)v.y +
                 (double)ringslot[k1] * (double)v.z + resL[k1] * (double)v.w;
        }
        zL[tid] = acc;
      }
      __syncthreads();
      if (tid < 128) {
        const double g = zL[j2], o = zL[j2 + 128];
        hL[j2] = (1.0 / (1.0 + exp(-g))) * tanh(o);
        ringslot[j2] = (float)resL[j2];  // enqueue layer INPUT res_l(t)
      }
      __syncthreads();

      // res' = res + h@Wres + bres ; skip += h@Wskip_l
      {
        const float4* wr = (const float4*)(Wres + ((size_t)(l * 128 + j2)) * 128 + kh * 64);
        const float4* wk = (const float4*)(Wskip + ((size_t)(l * 128 + j2)) * 128 + kh * 64);
        double pr = 0.0, ps = 0.0;
        for (int k4 = 0; k4 < 16; k4++) {
          const float4 a = wr[k4];
          const float4 c = wk[k4];
          const int bb = kh * 64 + 4 * k4;
          const double h0 = hL[bb], h1 = hL[bb + 1], h2 = hL[bb + 2], h3 = hL[bb + 3];
          pr += h0 * (double)a.x + h1 * (double)a.y + h2 * (double)a.z + h3 * (double)a.w;
          ps += h0 * (double)c.x + h1 * (double)c.y + h2 * (double)c.z + h3 * (double)c.w;
        }
        partA[tid] = pr;
        partB[tid] = ps;
      }
      __syncthreads();
      if (tid < 128) {
        resL[j2] = resL[j2] + partA[j2] + partA[j2 + 128] + (double)bres[l * 128 + j2];
        skipL[j2] += partB[j2] + partB[j2 + 128];
      }
      __syncthreads();
      pfx += dl;
    }

    // s1 = relu(skip) @ Wfc.T + bfc + cond_top
    if (tid < 128) tmpL[j2] = fmax(skipL[j2], 0.0);
    __syncthreads();
    {
      const float4* wr = (const float4*)(Wfcw + (size_t)j2 * 128 + kh * 64);
      double p = 0.0;
      for (int k4 = 0; k4 < 16; k4++) {
        const float4 v = wr[k4];
        const int bb = kh * 64 + 4 * k4;
        p += tmpL[bb] * (double)v.x + tmpL[bb + 1] * (double)v.y +
             tmpL[bb + 2] * (double)v.z + tmpL[bb + 3] * (double)v.w;
      }
      partA[tid] = p;
    }
    __syncthreads();
    if (tid < 128)
      s1L[j2] = fmax(partA[j2] + partA[j2 + 128] + bfcv + ct2L[e * 128 + j2], 0.0);
    __syncthreads();

    // logits_c = relu(s1) @ Wlogits[c][:] + blogits[c]   (c = tid)
    double lg = blgv;
    {
      const float4* wr = (const float4*)(Wlg + (size_t)tid * 128);
      for (int k4 = 0; k4 < 32; k4++) {
        const float4 v = wr[k4];
        const int bb = 4 * k4;
        lg += s1L[bb] * (double)v.x + s1L[bb + 1] * (double)v.y +
              s1L[bb + 2] * (double)v.z + s1L[bb + 3] * (double)v.w;
      }
    }

    // argmax over 256 classes, np first-max tie rule
    double bv = lg;
    int bi = tid;
    for (int off = 32; off >= 1; off >>= 1) {
      const double ov = __shfl_down(bv, (unsigned)off);
      const int oi = __shfl_down(bi, (unsigned)off);
      if (ov > bv || (ov == bv && oi < bi)) { bv = ov; bi = oi; }
    }
    if (lane == 0) { amaxv[w] = bv; amaxi[w] = bi; }
    __syncthreads();
    if (tid == 0) {
      double m = amaxv[0];
      int ii = amaxi[0];
      for (int w2 = 1; w2 < 4; w2++)
        if (amaxv[w2] > m || (amaxv[w2] == m && amaxi[w2] < ii)) { m = amaxv[w2]; ii = amaxi[w2]; }
      argix[0] = ii;
    }
    __syncthreads();
    fq = x;
    x = (double)((float)argix[0] / 127.5f - 1.f);  // mimic reference f32 math

    dout[((size_t)b * 256 + tid) * TSTEPS + t] = (float)lg;  // f32 output
  }
}

extern "C" void kernel_launch(void* const* d_in, const int* in_sizes, int n_in,
                              void* d_out, int out_size, void* d_ws, size_t ws_size,
                              hipStream_t stream) {
  (void)in_sizes; (void)n_in; (void)out_size; (void)ws_size;
  wn_mono<<<4, 256, 0, stream>>>(
      (const float*)d_in[0], (const float*)d_in[1], (const float*)d_in[2],
      (const float*)d_in[3], (const float*)d_in[4], (const float*)d_in[5],
      (const float*)d_in[6], (const float*)d_in[7], (const float*)d_in[8],
      (const float*)d_in[9], (const float*)d_in[10], (const float*)d_in[11],
      (const float*)d_in[12], (const float*)d_in[13], (const float*)d_in[14],
      (const float*)d_in[15], (const float*)d_in[16],
      (float*)d_out, (unsigned char*)d_ws);
}

// Round 7
// 34037.357 us; speedup vs baseline: 5.7279x; 5.7279x over previous
//
#include <hip/hip_runtime.h>

// WaveNet autoregressive generator, MI355X. Inputs fp32, OUTPUT fp32.
// Round 7: round-4 pipelined design (trajectory proven correct by the
// identical-6.5 forensics) with the single fix: fp32 output writes.
// 4 independent per-batch pipelines (batch == XCD id), 17 persistent blocks
// each (16 layer blocks + head), one CU per block. All matmuls are per-batch
// fp32 matrix-vector products on the VALU (exact); weights VGPR-resident or
// L2-streamed. Same-XCD mailboxes: tagged (fp32|step) u64, relaxed agent
// atomics. Dilated past-terms precomputed one step ahead from a per-layer
// res-history ring. Spin timeouts + global abort guarantee termination.

typedef unsigned long long u64;

#define TSTEPS 800
#define CREP 200

#define CTR_OFF 0
#define ABT_OFF 64
#define RESBOX_OFF 4096
#define BOXB 16384  // per-batch: 16 channels * 128 * 8B
#define SKIPBOX_OFF (RESBOX_OFF + 4 * BOXB)
#define RING_OFF (SKIPBOX_OFF + 4 * BOXB)
#define RINGB 261120  // per-batch: 510 slots * 128 * 4B
#define WS_END (RING_OFF + 4 * RINGB)

#define SPIN_LIMIT 1048576

static __device__ __forceinline__ void pub64(u64* p, float x, unsigned tag) {
  __hip_atomic_store(p, (u64)__float_as_uint(x) | ((u64)tag << 32),
                     __ATOMIC_RELAXED, __HIP_MEMORY_SCOPE_AGENT);
}
static __device__ __forceinline__ u64 ld64(const u64* p) {
  return __hip_atomic_load(p, __ATOMIC_RELAXED, __HIP_MEMORY_SCOPE_AGENT);
}
static __device__ __forceinline__ unsigned ld32(const unsigned* p) {
  return __hip_atomic_load(p, __ATOMIC_RELAXED, __HIP_MEMORY_SCOPE_AGENT);
}
static __device__ __forceinline__ void st32(unsigned* p, unsigned v) {
  __hip_atomic_store(p, v, __ATOMIC_RELAXED, __HIP_MEMORY_SCOPE_AGENT);
}
static __device__ __forceinline__ float spinf(const u64* p, unsigned tag, unsigned* abt) {
  int g = 0;
  for (;;) {
    const u64 v = ld64(p);
    if ((unsigned)(v >> 32) == tag) return __uint_as_float((unsigned)v);
    if (((++g) & 255) == 0) {
      if (g > SPIN_LIMIT || ld32(abt)) { st32(abt, 1u); return 0.f; }
    }
  }
}

__global__ void wn_init(unsigned char* ws) {
  uint4 z; z.x = 0; z.y = 0; z.z = 0; z.w = 0;
  uint4* p = (uint4*)ws;
  const int n = WS_END / 16;
  for (int i = blockIdx.x * blockDim.x + threadIdx.x; i < n; i += gridDim.x * blockDim.x)
    p[i] = z;
}

__global__ __launch_bounds__(256, 1) void wn_main(
    const float* __restrict__ enc, const float* __restrict__ Wfirst,
    const float* __restrict__ bfirst, const float* __restrict__ Wc,
    const float* __restrict__ bcv, const float* __restrict__ Wcond,
    const float* __restrict__ Wres, const float* __restrict__ bres,
    const float* __restrict__ Wskip, const float* __restrict__ bskipl,
    const float* __restrict__ Wskip0, const float* __restrict__ bskip0,
    const float* __restrict__ Wct, const float* __restrict__ Wfcw,
    const float* __restrict__ bfc, const float* __restrict__ Wlg,
    const float* __restrict__ blgg, float* __restrict__ dout,
    unsigned char* __restrict__ ws) {
  __shared__ __attribute__((aligned(16))) unsigned char smem[7680];
  float* zbS = (float*)smem;                 // layer: [4][256]
  float* ct2 = (float*)smem;                 // head: [4][128]
  float* res0S = (float*)(smem + 2048);      // head: [128]
  float* skS = (float*)(smem + 2560);        // head: [128]
  float* s1S = (float*)(smem + 3072);        // head: [128]
  float* resS = (float*)(smem + 4096);       // layer: [128]
  float* zS = (float*)(smem + 4608);         // layer: [256]
  float* hS = (float*)(smem + 5632);         // layer: [128]
  float* partS = (float*)(smem + 6144);      // both: [256]
  float* amaxv = (float*)(smem + 7168);      // [4]
  int* amaxi = (int*)(smem + 7184);          // [4]
  int* argixS = (int*)(smem + 7200);
  int* roleS = (int*)(smem + 7216);

  const int tid = threadIdx.x;
  unsigned* abt = (unsigned*)(ws + ABT_OFF);

  if (tid == 0) {
    unsigned xcc;
    asm volatile("s_getreg_b32 %0, hwreg(HW_REG_XCC_ID)" : "=s"(xcc));
    int role = 999;
    if (xcc < 4)
      role = (int)__hip_atomic_fetch_add((unsigned*)(ws + CTR_OFF) + xcc, 1u,
                                         __ATOMIC_RELAXED, __HIP_MEMORY_SCOPE_AGENT);
    roleS[0] = role;
    roleS[1] = (int)xcc;
  }
  __syncthreads();
  const int role = roleS[0];
  const int b = roleS[1];
  if (role >= 17) return;

  const int j2 = tid & 127, kh = tid >> 7;

  if (role < 16) {
    // ================= layer block =================
    const int l = role;
    const int dl = 1 << (l & 7);
    const int pfx = (l < 8) ? ((1 << l) - 1) : (254 + (1 << (l - 8)));

    float wc0r[128], wc1r[128], wresr[64];
#pragma unroll
    for (int k = 0; k < 64; k++) {
      const float4 v = ((const float4*)Wc)[(size_t)(l * 256 + tid) * 64 + k];
      wc0r[2 * k] = v.x; wc1r[2 * k] = v.y; wc0r[2 * k + 1] = v.z; wc1r[2 * k + 1] = v.w;
    }
#pragma unroll
    for (int k = 0; k < 16; k++) {
      const float4 v = ((const float4*)(Wres + (size_t)(l * 128 + j2) * 128 + kh * 64))[k];
      wresr[4 * k] = v.x; wresr[4 * k + 1] = v.y; wresr[4 * k + 2] = v.z; wresr[4 * k + 3] = v.w;
    }
    const float bresv = bres[l * 128 + j2];

    // cond+bias bases: zb[e][j] = bc[l][j] + c_e(b) @ Wcond[l][j][:]
    for (int e = 0; e < 4; e++) {
      float a = bcv[l * 256 + tid];
      for (int c = 0; c < 64; c++)
        a = fmaf(enc[(b * 64 + c) * 4 + e], Wcond[((size_t)l * 256 + tid) * 64 + c], a);
      zbS[e * 256 + tid] = a;
    }

    u64* inbox = (u64*)(ws + RESBOX_OFF + (size_t)b * BOXB) + l * 128;
    u64* outbox = (u64*)(ws + RESBOX_OFF + (size_t)b * BOXB) + ((l + 1) & 15) * 128;
    u64* skipbox = (u64*)(ws + SKIPBOX_OFF + (size_t)b * BOXB) + l * 128;
    float* ringf = (float*)(ws + RING_OFF + (size_t)b * RINGB) + pfx * 128;
    float pp = 0.f;  // past-term q(t)@Wc0 for current step (zero queues at t=0)
    __syncthreads();

    for (int t = 0; t < TSTEPS; t++) {
      const unsigned want = (unsigned)(t + 1);
      const int e = t / CREP;

      if (tid < 128) resS[tid] = spinf(inbox + tid, want, abt);
      __syncthreads();

      // z_j = past + (bc + cond) + res @ Wc1[j]
      float z = pp + zbS[e * 256 + tid];
      {
        const float4* r4 = (const float4*)resS;
#pragma unroll
        for (int k = 0; k < 32; k++) {
          const float4 r = r4[k];
          z = fmaf(r.x, wc1r[4 * k], z);
          z = fmaf(r.y, wc1r[4 * k + 1], z);
          z = fmaf(r.z, wc1r[4 * k + 2], z);
          z = fmaf(r.w, wc1r[4 * k + 3], z);
        }
      }
      zS[tid] = z;
      __syncthreads();
      if (tid < 128) {
        const float g = zS[tid], o = zS[tid + 128];
        hS[tid] = (1.f / (1.f + expf(-g))) * tanhf(o);
      }
      __syncthreads();

      if (l < 15) {
        // res' = res + h @ Wres + bres  (critical path -> publish first)
        const float4* h4 = (const float4*)(hS + kh * 64);
        float p = 0.f;
#pragma unroll
        for (int k = 0; k < 16; k++) {
          const float4 hv = h4[k];
          p = fmaf(hv.x, wresr[4 * k], p);
          p = fmaf(hv.y, wresr[4 * k + 1], p);
          p = fmaf(hv.z, wresr[4 * k + 2], p);
          p = fmaf(hv.w, wresr[4 * k + 3], p);
        }
        partS[tid] = p;
        __syncthreads();
        if (tid < 128)
          pub64(outbox + tid, resS[tid] + partS[tid] + partS[tid + 128] + bresv, want);
        __syncthreads();
      }

      // skip_l = h @ Wskip_l (weights streamed from L2; head adds biases)
      {
        const float4* wr = (const float4*)(Wskip + (size_t)(l * 128 + j2) * 128 + kh * 64);
        const float4* h4 = (const float4*)(hS + kh * 64);
        float p = 0.f;
#pragma unroll
        for (int k = 0; k < 16; k++) {
          const float4 wv = wr[k];
          const float4 hv = h4[k];
          p = fmaf(wv.x, hv.x, p);
          p = fmaf(wv.y, hv.y, p);
          p = fmaf(wv.z, hv.z, p);
          p = fmaf(wv.w, hv.w, p);
        }
        partS[tid] = p;
      }
      __syncthreads();
      if (tid < 128) pub64(skipbox + tid, partS[tid] + partS[tid + 128], want);

      // res history ring; precompute next step's past term (off-path)
      if (tid < 128) ringf[(t % dl) * 128 + tid] = resS[tid];
      __syncthreads();
      {
        const float4* src = (const float4*)(ringf + ((t + 1) % dl) * 128);
        float p2 = 0.f;
#pragma unroll
        for (int k = 0; k < 32; k++) {
          const float4 rv = src[k];
          p2 = fmaf(rv.x, wc0r[4 * k], p2);
          p2 = fmaf(rv.y, wc0r[4 * k + 1], p2);
          p2 = fmaf(rv.z, wc0r[4 * k + 2], p2);
          p2 = fmaf(rv.w, wc0r[4 * k + 3], p2);
        }
        pp = p2;
      }
    }
  } else {
    // ================= head block =================
    float wfcr[64], wlgr[128];
#pragma unroll
    for (int k = 0; k < 16; k++) {
      const float4 v = ((const float4*)(Wfcw + (size_t)j2 * 128 + kh * 64))[k];
      wfcr[4 * k] = v.x; wfcr[4 * k + 1] = v.y; wfcr[4 * k + 2] = v.z; wfcr[4 * k + 3] = v.w;
    }
#pragma unroll
    for (int k = 0; k < 32; k++) {
      const float4 v = ((const float4*)(Wlg + (size_t)tid * 128))[k];
      wlgr[4 * k] = v.x; wlgr[4 * k + 1] = v.y; wlgr[4 * k + 2] = v.z; wlgr[4 * k + 3] = v.w;
    }
    const float wf0 = Wfirst[2 * j2], wf1 = Wfirst[2 * j2 + 1], bfv = bfirst[j2];
    const float bs0 = bskip0[j2];
    float bsum = 0.f;
    for (int l2 = 0; l2 < 16; l2++) bsum += bskipl[l2 * 128 + j2];
    const float bfcv = bfc[j2];
    const float blgv = blgg[tid];
    if (tid < 128) {
      for (int e = 0; e < 4; e++) {
        float a = 0.f;
        for (int c = 0; c < 64; c++)
          a = fmaf(enc[(b * 64 + c) * 4 + e], Wct[tid * 64 + c], a);
        ct2[e * 128 + tid] = a;
      }
    }
    float fq = 0.f, x = 128.f / 127.5f - 1.f;
    u64* res0box = (u64*)(ws + RESBOX_OFF + (size_t)b * BOXB);  // layer-0 inbox
    const u64* skb = (const u64*)(ws + SKIPBOX_OFF + (size_t)b * BOXB);
    __syncthreads();

    for (int t = 0; t < TSTEPS; t++) {
      const unsigned want = (unsigned)(t + 1);
      const int e = t / CREP;

      // first causal conv; publish res0 immediately (starts the ring)
      if (tid < 128) {
        const float rv = fmaf(fq, wf0, fmaf(x, wf1, bfv));
        pub64(res0box + tid, rv, want);
        res0S[tid] = rv;
      }
      __syncthreads();

      // skip0 = res0 @ Wskip0 (streamed)
      {
        const float4* wr = (const float4*)(Wskip0 + (size_t)j2 * 128 + kh * 64);
        const float4* h4 = (const float4*)(res0S + kh * 64);
        float p = 0.f;
#pragma unroll
        for (int k = 0; k < 16; k++) {
          const float4 wv = wr[k];
          const float4 hv = h4[k];
          p = fmaf(wv.x, hv.x, p);
          p = fmaf(wv.y, hv.y, p);
          p = fmaf(wv.z, hv.z, p);
          p = fmaf(wv.w, hv.w, p);
        }
        partS[tid] = p;
      }
      __syncthreads();
      if (tid < 128) {
        float sacc = partS[tid] + partS[tid + 128] + bs0 + bsum;
        for (int l2 = 0; l2 < 16; l2++)
          sacc += spinf(skb + l2 * 128 + tid, want, abt);
        skS[tid] = fmaxf(sacc, 0.f);
      }
      __syncthreads();

      // s1 = relu(skip) @ Wfc + bfc + cond_top
      {
        const float4* h4 = (const float4*)(skS + kh * 64);
        float p = 0.f;
#pragma unroll
        for (int k = 0; k < 16; k++) {
          const float4 hv = h4[k];
          p = fmaf(hv.x, wfcr[4 * k], p);
          p = fmaf(hv.y, wfcr[4 * k + 1], p);
          p = fmaf(hv.z, wfcr[4 * k + 2], p);
          p = fmaf(hv.w, wfcr[4 * k + 3], p);
        }
        partS[tid] = p;
      }
      __syncthreads();
      if (tid < 128)
        s1S[tid] = fmaxf(partS[tid] + partS[tid + 128] + bfcv + ct2[e * 128 + tid], 0.f);
      __syncthreads();

      // logits = relu(s1) @ Wlogits + blogits
      float lg = blgv;
      {
        const float4* h4 = (const float4*)s1S;
#pragma unroll
        for (int k = 0; k < 32; k++) {
          const float4 hv = h4[k];
          lg = fmaf(hv.x, wlgr[4 * k], lg);
          lg = fmaf(hv.y, wlgr[4 * k + 1], lg);
          lg = fmaf(hv.z, wlgr[4 * k + 2], lg);
          lg = fmaf(hv.w, wlgr[4 * k + 3], lg);
        }
      }

      // argmax (np first-max tie rule)
      float bv = lg;
      int bi = tid;
#pragma unroll
      for (int off = 32; off >= 1; off >>= 1) {
        const float ov = __shfl_down(bv, (unsigned)off);
        const int oi = __shfl_down(bi, (unsigned)off);
        if (ov > bv || (ov == bv && oi < bi)) { bv = ov; bi = oi; }
      }
      if ((tid & 63) == 0) { amaxv[tid >> 6] = bv; amaxi[tid >> 6] = bi; }
      __syncthreads();
      if (tid == 0) {
        float bb = amaxv[0];
        int ii = amaxi[0];
        for (int w2 = 1; w2 < 4; w2++)
          if (amaxv[w2] > bb || (amaxv[w2] == bb && amaxi[w2] < ii)) { bb = amaxv[w2]; ii = amaxi[w2]; }
        argixS[0] = ii;
      }
      __syncthreads();
      fq = x;
      x = (float)argixS[0] / 127.5f - 1.f;

      dout[((size_t)b * 256 + tid) * TSTEPS + t] = lg;  // fp32 output
    }
  }
}

extern "C" void kernel_launch(void* const* d_in, const int* in_sizes, int n_in,
                              void* d_out, int out_size, void* d_ws, size_t ws_size,
                              hipStream_t stream) {
  (void)in_sizes; (void)n_in; (void)out_size; (void)ws_size;
  wn_init<<<256, 256, 0, stream>>>((unsigned char*)d_ws);
  wn_main<<<1024, 256, 0, stream>>>(
      (const float*)d_in[0], (const float*)d_in[1], (const float*)d_in[2],
      (const float*)d_in[3], (const float*)d_in[4], (const float*)d_in[5],
      (const float*)d_in[6], (const float*)d_in[7], (const float*)d_in[8],
      (const float*)d_in[9], (const float*)d_in[10], (const float*)d_in[11],
      (const float*)d_in[12], (const float*)d_in[13], (const float*)d_in[14],
      (const float*)d_in[15], (const float*)d_in[16],
      (float*)d_out, (unsigned char*)d_ws);
}

// Round 10
// 27388.959 us; speedup vs baseline: 7.1183x; 1.2427x over previous
//
#include <hip/hip_runtime.h>

// WaveNet autoregressive generator, MI355X. Inputs fp32, OUTPUT fp32.
// Round 10: mailboxes via INLINE-ASM L2 atomics. R9's atomic_fetch_add(p,0)
// was InstCombine'd into a plain workgroup-scope load (L1-served, stale
// forever -> abort cascade). Hardware truth: global_atomic_* ALWAYS executes
// in the L2 atomic units (L1 cannot do atomics), so inline-asm atomics give
// un-optimizable XCD-L2-coherent messaging: publish = global_atomic_swap_x2
// (no sc1 -> stays in XCD L2), poll = global_atomic_add_x2 with 0 + sc0
// (returns L2 contents). Same-XCD by construction (XCC_ID role claim).
// Head polls 16 skip boxes as 4x4 concurrent in-flight atomics.

typedef unsigned long long u64;

#define TSTEPS 800
#define CREP 200

#define CTR_OFF 0
#define ABT_OFF 64
#define RESBOX_OFF 4096
#define BOXB 16384  // per-batch: 16 channels * 128 * 8B
#define SKIPBOX_OFF (RESBOX_OFF + 4 * BOXB)
#define RING_OFF (SKIPBOX_OFF + 4 * BOXB)
#define RINGB 261120  // per-batch: 510 slots * 128 * 4B
#define WS_END (RING_OFF + 4 * RINGB)

#define SPIN_LIMIT 1048576

// ---- XCD-L2 mailbox ops (inline asm: atomics execute in L2, always) ----
static __device__ __forceinline__ void pub64(u64* p, float x, unsigned tag) {
  const u64 v = (u64)__float_as_uint(x) | ((u64)tag << 32);
  asm volatile("global_atomic_swap_x2 %0, %1, off" ::"v"(p), "v"(v) : "memory");
}
static __device__ __forceinline__ u64 poll64(u64* p) {
  u64 old;
  const u64 z = 0;
  asm volatile("global_atomic_add_x2 %0, %1, %2, off sc0\n\ts_waitcnt vmcnt(0)"
               : "=&v"(old) : "v"(p), "v"(z) : "memory");
  return old;
}
// 4 concurrent polls at +0/+1024/+2048/+3072 bytes (one vmcnt wait)
static __device__ __forceinline__ void poll4(u64* p, u64& a, u64& b, u64& c, u64& d) {
  const u64 z = 0;
  asm volatile(
      "global_atomic_add_x2 %0, %4, %5, off sc0\n\t"
      "global_atomic_add_x2 %1, %4, %5, off offset:1024 sc0\n\t"
      "global_atomic_add_x2 %2, %4, %5, off offset:2048 sc0\n\t"
      "global_atomic_add_x2 %3, %4, %5, off offset:3072 sc0\n\t"
      "s_waitcnt vmcnt(0)"
      : "=&v"(a), "=&v"(b), "=&v"(c), "=&v"(d)
      : "v"(p), "v"(z)
      : "memory");
}
// ---- device-scope (rare, off hot path) ----
static __device__ __forceinline__ unsigned ld32(const unsigned* p) {
  return __hip_atomic_load(p, __ATOMIC_RELAXED, __HIP_MEMORY_SCOPE_AGENT);
}
static __device__ __forceinline__ void st32(unsigned* p, unsigned v) {
  __hip_atomic_store(p, v, __ATOMIC_RELAXED, __HIP_MEMORY_SCOPE_AGENT);
}
static __device__ __forceinline__ float spinf(u64* p, unsigned tag, unsigned* abt) {
  int g = 0;
  for (;;) {
    const u64 v = poll64(p);
    if ((unsigned)(v >> 32) == tag) return __uint_as_float((unsigned)v);
    if (((++g) & 255) == 0) {
      if (g > SPIN_LIMIT || ld32(abt)) { st32(abt, 1u); return 0.f; }
    }
  }
}

__global__ void wn_init(unsigned char* ws) {
  uint4 z; z.x = 0; z.y = 0; z.z = 0; z.w = 0;
  uint4* p = (uint4*)ws;
  const int n = WS_END / 16;
  for (int i = blockIdx.x * blockDim.x + threadIdx.x; i < n; i += gridDim.x * blockDim.x)
    p[i] = z;
}

__global__ __launch_bounds__(256, 1) void wn_main(
    const float* __restrict__ enc, const float* __restrict__ Wfirst,
    const float* __restrict__ bfirst, const float* __restrict__ Wc,
    const float* __restrict__ bcv, const float* __restrict__ Wcond,
    const float* __restrict__ Wres, const float* __restrict__ bres,
    const float* __restrict__ Wskip, const float* __restrict__ bskipl,
    const float* __restrict__ Wskip0, const float* __restrict__ bskip0,
    const float* __restrict__ Wct, const float* __restrict__ Wfcw,
    const float* __restrict__ bfc, const float* __restrict__ Wlg,
    const float* __restrict__ blgg, float* __restrict__ dout,
    unsigned char* __restrict__ ws) {
  __shared__ __attribute__((aligned(16))) unsigned char smem[8192];
  float* zbS = (float*)smem;                 // layer: [4][256]
  float* ct2 = (float*)smem;                 // head: [4][128]
  float* res0S = (float*)(smem + 2048);      // head: [128]
  float* skS = (float*)(smem + 2560);        // head: [128]
  float* s1S = (float*)(smem + 3072);        // head: [128]
  float* resS = (float*)(smem + 4096);       // layer: [128]
  float* zS = (float*)(smem + 4608);         // layer: [256]
  float* hS = (float*)(smem + 5632);         // layer: [128]
  float* partS = (float*)(smem + 6144);      // both: [256]
  float* amaxv = (float*)(smem + 7168);      // [4]
  int* amaxi = (int*)(smem + 7184);          // [4]
  int* argixS = (int*)(smem + 7200);
  int* roleS = (int*)(smem + 7216);
  float* pastS = (float*)(smem + 7424);      // layer: [128]

  const int tid = threadIdx.x;
  unsigned* abt = (unsigned*)(ws + ABT_OFF);

  if (tid == 0) {
    unsigned xcc;
    asm volatile("s_getreg_b32 %0, hwreg(HW_REG_XCC_ID)" : "=s"(xcc));
    int role = 999;
    if (xcc < 4)
      role = (int)__hip_atomic_fetch_add((unsigned*)(ws + CTR_OFF) + xcc, 1u,
                                         __ATOMIC_RELAXED, __HIP_MEMORY_SCOPE_AGENT);
    roleS[0] = role;
    roleS[1] = (int)xcc;
  }
  __syncthreads();
  const int role = roleS[0];
  const int b = roleS[1];
  if (role >= 17) return;

  const int j2 = tid & 127, kh = tid >> 7;

  if (role < 16) {
    // ================= layer block =================
    const int l = role;
    const int dl = 1 << (l & 7);
    const int pfx = (l < 8) ? ((1 << l) - 1) : (254 + (1 << (l - 8)));

    // VGPR-resident critical-path weights (192 floats/thread, no spill)
    float wc1r[128], wresr[64];
#pragma unroll
    for (int k = 0; k < 64; k++) {
      const float4 v = ((const float4*)Wc)[(size_t)(l * 256 + tid) * 64 + k];
      wc1r[2 * k] = v.y; wc1r[2 * k + 1] = v.w;  // tap-1 (current res)
    }
#pragma unroll
    for (int k = 0; k < 16; k++) {
      const float4 v = ((const float4*)(Wres + (size_t)(l * 128 + j2) * 128 + kh * 64))[k];
      wresr[4 * k] = v.x; wresr[4 * k + 1] = v.y; wresr[4 * k + 2] = v.z; wresr[4 * k + 3] = v.w;
    }
    const float bresv = bres[l * 128 + j2];

    // cond+bias bases: zb[e][j] = bc[l][j] + c_e(b) @ Wcond[l][j][:]
    for (int e = 0; e < 4; e++) {
      float a = bcv[l * 256 + tid];
      for (int c = 0; c < 64; c++)
        a = fmaf(enc[(b * 64 + c) * 4 + e], Wcond[((size_t)l * 256 + tid) * 64 + c], a);
      zbS[e * 256 + tid] = a;
    }

    u64* inbox = (u64*)(ws + RESBOX_OFF + (size_t)b * BOXB) + l * 128;
    u64* outbox = (u64*)(ws + RESBOX_OFF + (size_t)b * BOXB) + ((l + 1) & 15) * 128;
    u64* skipbox = (u64*)(ws + SKIPBOX_OFF + (size_t)b * BOXB) + l * 128;
    float* ringf = (float*)(ws + RING_OFF + (size_t)b * RINGB) + pfx * 128;
    float pp = 0.f;  // past-term q(t)@Wc0 for current step (zero queues at t=0)
    __syncthreads();

    for (int t = 0; t < TSTEPS; t++) {
      const unsigned want = (unsigned)(t + 1);
      const int e = t / CREP;

      if (tid < 128) resS[tid] = spinf(inbox + tid, want, abt);
      __syncthreads();

      // z_j = past + (bc + cond) + res @ Wc1[j]   (all VGPR weights)
      float z = pp + zbS[e * 256 + tid];
      {
        const float4* r4 = (const float4*)resS;
#pragma unroll
        for (int k = 0; k < 32; k++) {
          const float4 r = r4[k];
          z = fmaf(r.x, wc1r[4 * k], z);
          z = fmaf(r.y, wc1r[4 * k + 1], z);
          z = fmaf(r.z, wc1r[4 * k + 2], z);
          z = fmaf(r.w, wc1r[4 * k + 3], z);
        }
      }
      zS[tid] = z;
      __syncthreads();
      if (tid < 128) {
        const float g = zS[tid], o = zS[tid + 128];
        hS[tid] = (1.f / (1.f + expf(-g))) * tanhf(o);
      }
      __syncthreads();

      if (l < 15) {
        // res' = res + h @ Wres + bres  (critical path -> publish first)
        const float4* h4 = (const float4*)(hS + kh * 64);
        float p = 0.f;
#pragma unroll
        for (int k = 0; k < 16; k++) {
          const float4 hv = h4[k];
          p = fmaf(hv.x, wresr[4 * k], p);
          p = fmaf(hv.y, wresr[4 * k + 1], p);
          p = fmaf(hv.z, wresr[4 * k + 2], p);
          p = fmaf(hv.w, wresr[4 * k + 3], p);
        }
        partS[tid] = p;
        __syncthreads();
        if (tid < 128)
          pub64(outbox + tid, resS[tid] + partS[tid] + partS[tid + 128] + bresv, want);
        __syncthreads();
      }

      // ---- everything below is off the pipeline critical path ----

      // skip_l = h @ Wskip_l (weights streamed from L1/L2)
      {
        const float4* wr = (const float4*)(Wskip + (size_t)(l * 128 + j2) * 128 + kh * 64);
        const float4* h4 = (const float4*)(hS + kh * 64);
        float p = 0.f;
#pragma unroll
        for (int k = 0; k < 16; k++) {
          const float4 wv = wr[k];
          const float4 hv = h4[k];
          p = fmaf(wv.x, hv.x, p);
          p = fmaf(wv.y, hv.y, p);
          p = fmaf(wv.z, hv.z, p);
          p = fmaf(wv.w, hv.w, p);
        }
        partS[tid] = p;
      }
      __syncthreads();
      if (tid < 128) pub64(skipbox + tid, partS[tid] + partS[tid + 128], want);

      // res history ring; stage next step's past input into LDS
      if (tid < 128) {
        ringf[(t % dl) * 128 + tid] = resS[tid];
        pastS[tid] = (dl == 1) ? resS[tid] : ringf[((t + 1) % dl) * 128 + tid];
      }
      __syncthreads();
      // next step's past term: pastS @ Wc0 (Wc streamed from L2; slack window)
      {
        const float4* wv4 = (const float4*)(Wc + (size_t)(l * 256 + tid) * 256);
        float p2 = 0.f;
#pragma unroll 8
        for (int k = 0; k < 64; k++) {
          const float4 v = wv4[k];
          p2 = fmaf(pastS[2 * k], v.x, p2);
          p2 = fmaf(pastS[2 * k + 1], v.z, p2);
        }
        pp = p2;
      }
    }
  } else {
    // ================= head block =================
    float wfcr[64], wlgr[128];
#pragma unroll
    for (int k = 0; k < 16; k++) {
      const float4 v = ((const float4*)(Wfcw + (size_t)j2 * 128 + kh * 64))[k];
      wfcr[4 * k] = v.x; wfcr[4 * k + 1] = v.y; wfcr[4 * k + 2] = v.z; wfcr[4 * k + 3] = v.w;
    }
#pragma unroll
    for (int k = 0; k < 32; k++) {
      const float4 v = ((const float4*)(Wlg + (size_t)tid * 128))[k];
      wlgr[4 * k] = v.x; wlgr[4 * k + 1] = v.y; wlgr[4 * k + 2] = v.z; wlgr[4 * k + 3] = v.w;
    }
    const float wf0 = Wfirst[2 * j2], wf1 = Wfirst[2 * j2 + 1], bfv = bfirst[j2];
    const float bs0 = bskip0[j2];
    float bsum = 0.f;
    for (int l2 = 0; l2 < 16; l2++) bsum += bskipl[l2 * 128 + j2];
    const float bfcv = bfc[j2];
    const float blgv = blgg[tid];
    if (tid < 128) {
      for (int e = 0; e < 4; e++) {
        float a = 0.f;
        for (int c = 0; c < 64; c++)
          a = fmaf(enc[(b * 64 + c) * 4 + e], Wct[tid * 64 + c], a);
        ct2[e * 128 + tid] = a;
      }
    }
    float fq = 0.f, x = 128.f / 127.5f - 1.f;
    u64* res0box = (u64*)(ws + RESBOX_OFF + (size_t)b * BOXB);  // layer-0 inbox
    u64* skb = (u64*)(ws + SKIPBOX_OFF + (size_t)b * BOXB);
    __syncthreads();

    for (int t = 0; t < TSTEPS; t++) {
      const unsigned want = (unsigned)(t + 1);
      const int e = t / CREP;

      // first causal conv; publish res0 immediately (starts the ring)
      if (tid < 128) {
        const float rv = fmaf(fq, wf0, fmaf(x, wf1, bfv));
        pub64(res0box + tid, rv, want);
        res0S[tid] = rv;
      }
      __syncthreads();

      // skip0 = res0 @ Wskip0 (streamed)
      {
        const float4* wr = (const float4*)(Wskip0 + (size_t)j2 * 128 + kh * 64);
        const float4* h4 = (const float4*)(res0S + kh * 64);
        float p = 0.f;
#pragma unroll
        for (int k = 0; k < 16; k++) {
          const float4 wv = wr[k];
          const float4 hv = h4[k];
          p = fmaf(wv.x, hv.x, p);
          p = fmaf(wv.y, hv.y, p);
          p = fmaf(wv.z, hv.z, p);
          p = fmaf(wv.w, hv.w, p);
        }
        partS[tid] = p;
      }
      __syncthreads();
      if (tid < 128) {
        float sacc = partS[tid] + partS[tid + 128] + bs0 + bsum;
        // poll all 16 per-layer skip boxes (4 groups x 4 concurrent atomics)
        u64 v[16];
        int g = 0;
        for (;;) {
          bool ok = true;
#pragma unroll
          for (int grp = 0; grp < 4; grp++)
            poll4(skb + grp * 512 + tid, v[grp * 4], v[grp * 4 + 1], v[grp * 4 + 2], v[grp * 4 + 3]);
#pragma unroll
          for (int l2 = 0; l2 < 16; l2++) ok &= ((unsigned)(v[l2] >> 32) == want);
          if (ok) break;
          if (((++g) & 63) == 0) {
            if (g > (SPIN_LIMIT >> 6) || ld32(abt)) { st32(abt, 1u); break; }
          }
        }
#pragma unroll
        for (int l2 = 0; l2 < 16; l2++) sacc += __uint_as_float((unsigned)v[l2]);
        skS[tid] = fmaxf(sacc, 0.f);
      }
      __syncthreads();

      // s1 = relu(skip) @ Wfc + bfc + cond_top
      {
        const float4* h4 = (const float4*)(skS + kh * 64);
        float p = 0.f;
#pragma unroll
        for (int k = 0; k < 16; k++) {
          const float4 hv = h4[k];
          p = fmaf(hv.x, wfcr[4 * k], p);
          p = fmaf(hv.y, wfcr[4 * k + 1], p);
          p = fmaf(hv.z, wfcr[4 * k + 2], p);
          p = fmaf(hv.w, wfcr[4 * k + 3], p);
        }
        partS[tid] = p;
      }
      __syncthreads();
      if (tid < 128)
        s1S[tid] = fmaxf(partS[tid] + partS[tid + 128] + bfcv + ct2[e * 128 + tid], 0.f);
      __syncthreads();

      // logits = relu(s1) @ Wlogits + blogits
      float lg = blgv;
      {
        const float4* h4 = (const float4*)s1S;
#pragma unroll
        for (int k = 0; k < 32; k++) {
          const float4 hv = h4[k];
          lg = fmaf(hv.x, wlgr[4 * k], lg);
          lg = fmaf(hv.y, wlgr[4 * k + 1], lg);
          lg = fmaf(hv.z, wlgr[4 * k + 2], lg);
          lg = fmaf(hv.w, wlgr[4 * k + 3], lg);
        }
      }

      // argmax (np first-max tie rule)
      float bv = lg;
      int bi = tid;
#pragma unroll
      for (int off = 32; off >= 1; off >>= 1) {
        const float ov = __shfl_down(bv, (unsigned)off);
        const int oi = __shfl_down(bi, (unsigned)off);
        if (ov > bv || (ov == bv && oi < bi)) { bv = ov; bi = oi; }
      }
      if ((tid & 63) == 0) { amaxv[tid >> 6] = bv; amaxi[tid >> 6] = bi; }
      __syncthreads();
      if (tid == 0) {
        float bb = amaxv[0];
        int ii = amaxi[0];
        for (int w2 = 1; w2 < 4; w2++)
          if (amaxv[w2] > bb || (amaxv[w2] == bb && amaxi[w2] < ii)) { bb = amaxv[w2]; ii = amaxi[w2]; }
        argixS[0] = ii;
      }
      __syncthreads();
      fq = x;
      x = (float)argixS[0] / 127.5f - 1.f;

      dout[((size_t)b * 256 + tid) * TSTEPS + t] = lg;  // fp32 output
    }
  }
}

extern "C" void kernel_launch(void* const* d_in, const int* in_sizes, int n_in,
                              void* d_out, int out_size, void* d_ws, size_t ws_size,
                              hipStream_t stream) {
  (void)in_sizes; (void)n_in; (void)out_size; (void)ws_size;
  wn_init<<<256, 256, 0, stream>>>((unsigned char*)d_ws);
  wn_main<<<1024, 256, 0, stream>>>(
      (const float*)d_in[0], (const float*)d_in[1], (const float*)d_in[2],
      (const float*)d_in[3], (const float*)d_in[4], (const float*)d_in[5],
      (const float*)d_in[6], (const float*)d_in[7], (const float*)d_in[8],
      (const float*)d_in[9], (const float*)d_in[10], (const float*)d_in[11],
      (const float*)d_in[12], (const float*)d_in[13], (const float*)d_in[14],
      (const float*)d_in[15], (const float*)d_in[16],
      (float*)d_out, (unsigned char*)d_ws);
}

// Round 11
// 23720.374 us; speedup vs baseline: 8.2192x; 1.1547x over previous
//
#include <hip/hip_runtime.h>

// WaveNet autoregressive generator, MI355X. Inputs fp32, OUTPUT fp32.
// Round 11: kill the L2 thrash (R10: FETCH 8.3GB/WRITE 3.5GB = Wc0+Wskip
// streaming + spilled weight arrays; 27-66ms variance). Blocks now 512
// threads; Wc1 AND Wc0 k-split across thread halves (64+64 floats), Wres
// k-quartered (32) -> 160 floats/thread, register-resident under
// __launch_bounds__(512,2). Partials combined in LDS. Only Wskip (64KB/step)
// still streams -> per-XCD working set << 4MB L2. Mailbox protocol is R10's
// proven inline-asm L2 atomics, unchanged.

typedef unsigned long long u64;

#define TSTEPS 800
#define CREP 200

#define CTR_OFF 0
#define ABT_OFF 64
#define RESBOX_OFF 4096
#define BOXB 16384  // per-batch: 16 channels * 128 * 8B
#define SKIPBOX_OFF (RESBOX_OFF + 4 * BOXB)
#define RING_OFF (SKIPBOX_OFF + 4 * BOXB)
#define RINGB 261120  // per-batch: 510 slots * 128 * 4B
#define WS_END (RING_OFF + 4 * RINGB)

#define SPIN_LIMIT 1048576

// ---- XCD-L2 mailbox ops (inline asm: atomics execute in L2, always) ----
static __device__ __forceinline__ void pub64(u64* p, float x, unsigned tag) {
  const u64 v = (u64)__float_as_uint(x) | ((u64)tag << 32);
  asm volatile("global_atomic_swap_x2 %0, %1, off" ::"v"(p), "v"(v) : "memory");
}
static __device__ __forceinline__ u64 poll64(u64* p) {
  u64 old;
  const u64 z = 0;
  asm volatile("global_atomic_add_x2 %0, %1, %2, off sc0\n\ts_waitcnt vmcnt(0)"
               : "=&v"(old) : "v"(p), "v"(z) : "memory");
  return old;
}
static __device__ __forceinline__ void poll4(u64* p, u64& a, u64& b, u64& c, u64& d) {
  const u64 z = 0;
  asm volatile(
      "global_atomic_add_x2 %0, %4, %5, off sc0\n\t"
      "global_atomic_add_x2 %1, %4, %5, off offset:1024 sc0\n\t"
      "global_atomic_add_x2 %2, %4, %5, off offset:2048 sc0\n\t"
      "global_atomic_add_x2 %3, %4, %5, off offset:3072 sc0\n\t"
      "s_waitcnt vmcnt(0)"
      : "=&v"(a), "=&v"(b), "=&v"(c), "=&v"(d)
      : "v"(p), "v"(z)
      : "memory");
}
// ---- device-scope (rare, off hot path) ----
static __device__ __forceinline__ unsigned ld32(const unsigned* p) {
  return __hip_atomic_load(p, __ATOMIC_RELAXED, __HIP_MEMORY_SCOPE_AGENT);
}
static __device__ __forceinline__ void st32(unsigned* p, unsigned v) {
  __hip_atomic_store(p, v, __ATOMIC_RELAXED, __HIP_MEMORY_SCOPE_AGENT);
}
static __device__ __forceinline__ float spinf(u64* p, unsigned tag, unsigned* abt) {
  int g = 0;
  for (;;) {
    const u64 v = poll64(p);
    if ((unsigned)(v >> 32) == tag) return __uint_as_float((unsigned)v);
    if (((++g) & 255) == 0) {
      if (g > SPIN_LIMIT || ld32(abt)) { st32(abt, 1u); return 0.f; }
    }
  }
}

__global__ void wn_init(unsigned char* ws) {
  uint4 z; z.x = 0; z.y = 0; z.z = 0; z.w = 0;
  uint4* p = (uint4*)ws;
  const int n = WS_END / 16;
  for (int i = blockIdx.x * blockDim.x + threadIdx.x; i < n; i += gridDim.x * blockDim.x)
    p[i] = z;
}

__global__ __launch_bounds__(512, 2) void wn_main(
    const float* __restrict__ enc, const float* __restrict__ Wfirst,
    const float* __restrict__ bfirst, const float* __restrict__ Wc,
    const float* __restrict__ bcv, const float* __restrict__ Wcond,
    const float* __restrict__ Wres, const float* __restrict__ bres,
    const float* __restrict__ Wskip, const float* __restrict__ bskipl,
    const float* __restrict__ Wskip0, const float* __restrict__ bskip0,
    const float* __restrict__ Wct, const float* __restrict__ Wfcw,
    const float* __restrict__ bfc, const float* __restrict__ Wlg,
    const float* __restrict__ blgg, float* __restrict__ dout,
    unsigned char* __restrict__ ws) {
  __shared__ __attribute__((aligned(16))) unsigned char smem[14336];
  float* zbS = (float*)smem;                   // layer: [4][256] (4KB)
  float* ct2 = (float*)smem;                   // head: [4][128] (2KB)
  float* resS = (float*)(smem + 4096);         // layer [128] / head res0S
  float* zpartS = (float*)(smem + 4608);       // [512] / head partS
  float* ppS = (float*)(smem + 6656);          // [512] / head lgS
  float* hS = (float*)(smem + 8704);           // [128] / head skS
  float* rpartS = (float*)(smem + 9216);       // [512] / head s1S[128]
  float* skpartS = (float*)(smem + 11264);     // [512]
  float* pastS = (float*)(smem + 13312);       // [128]
  float* amaxv = (float*)(smem + 13824);       // [4]
  int* amaxi = (int*)(smem + 13840);           // [4]
  int* argixS = (int*)(smem + 13856);
  int* roleS = (int*)(smem + 13872);

  const int tid = threadIdx.x;
  unsigned* abt = (unsigned*)(ws + ABT_OFF);

  if (tid == 0) {
    unsigned xcc;
    asm volatile("s_getreg_b32 %0, hwreg(HW_REG_XCC_ID)" : "=s"(xcc));
    int role = 999;
    if (xcc < 4)
      role = (int)__hip_atomic_fetch_add((unsigned*)(ws + CTR_OFF) + xcc, 1u,
                                         __ATOMIC_RELAXED, __HIP_MEMORY_SCOPE_AGENT);
    roleS[0] = role;
    roleS[1] = (int)xcc;
  }
  __syncthreads();
  const int role = roleS[0];
  const int b = roleS[1];
  if (role >= 17) return;

  const int jz = tid & 255, kh = tid >> 8;        // z-split: output jz, k-half kh
  const int j3 = tid & 127, q3 = tid >> 7;        // r-split: output j3, k-quarter q3

  if (role < 16) {
    // ================= layer block =================
    const int l = role;
    const int dl = 1 << (l & 7);
    const int pfx = (l < 8) ? ((1 << l) - 1) : (254 + (1 << (l - 8)));

    // Register-resident weights: 64+64+32 = 160 floats/thread.
    float wc1h[64], wc0h[64], wresq[32];
    {
      const float4* wbase = (const float4*)(Wc + ((size_t)(l * 256 + jz) * 128 + kh * 64) * 2);
#pragma unroll
      for (int m = 0; m < 32; m++) {
        const float4 v = wbase[m];  // {tap0(k), tap1(k), tap0(k+1), tap1(k+1)}
        wc0h[2 * m] = v.x; wc1h[2 * m] = v.y;
        wc0h[2 * m + 1] = v.z; wc1h[2 * m + 1] = v.w;
      }
      const float4* rbase = (const float4*)(Wres + (size_t)(l * 128 + j3) * 128 + q3 * 32);
#pragma unroll
      for (int m = 0; m < 8; m++) {
        const float4 v = rbase[m];
        wresq[4 * m] = v.x; wresq[4 * m + 1] = v.y;
        wresq[4 * m + 2] = v.z; wresq[4 * m + 3] = v.w;
      }
    }
    const float bresv = bres[l * 128 + j3];

    // zb[e][j] = bc[l][j] + c_e(b) @ Wcond[l][j][:]  (tid<256)
    if (tid < 256) {
      for (int e = 0; e < 4; e++) {
        float a = bcv[l * 256 + tid];
        for (int c = 0; c < 64; c++)
          a = fmaf(enc[(b * 64 + c) * 4 + e], Wcond[((size_t)l * 256 + tid) * 64 + c], a);
        zbS[e * 256 + tid] = a;
      }
    }
    ppS[tid] = 0.f;  // past-term partials start at zero (zero queues)

    u64* inbox = (u64*)(ws + RESBOX_OFF + (size_t)b * BOXB) + l * 128;
    u64* outbox = (u64*)(ws + RESBOX_OFF + (size_t)b * BOXB) + ((l + 1) & 15) * 128;
    u64* skipbox = (u64*)(ws + SKIPBOX_OFF + (size_t)b * BOXB) + l * 128;
    float* ringf = (float*)(ws + RING_OFF + (size_t)b * RINGB) + pfx * 128;
    const float4* wskb = (const float4*)(Wskip + (size_t)(l * 128 + j3) * 128 + q3 * 32);
    __syncthreads();

    for (int t = 0; t < TSTEPS; t++) {
      const unsigned want = (unsigned)(t + 1);
      const int e = t / CREP;

      if (tid < 128) resS[tid] = spinf(inbox + tid, want, abt);
      __syncthreads();

      // z partials: zpart[kh][jz] = sum_k res[kh*64+k] * Wc1[jz][kh*64+k]
      {
        const float* rp = resS + kh * 64;
        float zp = 0.f;
#pragma unroll
        for (int kk = 0; kk < 64; kk++) zp = fmaf(rp[kk], wc1h[kk], zp);
        zpartS[(kh << 8) | jz] = zp;
      }
      __syncthreads();
      if (tid < 128) {
        const float g0 = zpartS[tid] + zpartS[256 + tid] + ppS[tid] + ppS[256 + tid] +
                         zbS[e * 256 + tid];
        const float o0 = zpartS[128 + tid] + zpartS[384 + tid] + ppS[128 + tid] +
                         ppS[384 + tid] + zbS[e * 256 + 128 + tid];
        hS[tid] = (1.f / (1.f + expf(-g0))) * tanhf(o0);
      }
      __syncthreads();

      // res' partials: rpart[q3][j3] = sum_k h[q3*32+k] * Wres[j3][q3*32+k]
      {
        const float* hp = hS + q3 * 32;
        float rp2 = 0.f;
#pragma unroll
        for (int kk = 0; kk < 32; kk++) rp2 = fmaf(hp[kk], wresq[kk], rp2);
        rpartS[(q3 << 7) | j3] = rp2;
      }
      __syncthreads();
      if (l < 15 && tid < 128)
        pub64(outbox + tid,
              resS[tid] + rpartS[tid] + rpartS[128 + tid] + rpartS[256 + tid] +
                  rpartS[384 + tid] + bresv,
              want);

      // ---- off critical path ----
      // skip partials (Wskip streamed; L2-resident after first step)
      {
        const float* hp = hS + q3 * 32;
        float sp = 0.f;
#pragma unroll
        for (int m = 0; m < 8; m++) {
          const float4 wv = wskb[m];
          sp = fmaf(hp[4 * m], wv.x, sp);
          sp = fmaf(hp[4 * m + 1], wv.y, sp);
          sp = fmaf(hp[4 * m + 2], wv.z, sp);
          sp = fmaf(hp[4 * m + 3], wv.w, sp);
        }
        skpartS[(q3 << 7) | j3] = sp;
      }
      __syncthreads();
      if (tid < 128)
        pub64(skipbox + tid,
              skpartS[tid] + skpartS[128 + tid] + skpartS[256 + tid] + skpartS[384 + tid],
              want);

      // res history ring; stage next step's past input
      if (tid < 128) {
        ringf[(t % dl) * 128 + tid] = resS[tid];
        pastS[tid] = (dl == 1) ? resS[tid] : ringf[((t + 1) % dl) * 128 + tid];
      }
      __syncthreads();
      // next step's past-term partials (VGPR wc0h)
      {
        const float* pp2 = pastS + kh * 64;
        float ppn = 0.f;
#pragma unroll
        for (int kk = 0; kk < 64; kk++) ppn = fmaf(pp2[kk], wc0h[kk], ppn);
        ppS[(kh << 8) | jz] = ppn;
      }
    }
  } else {
    // ================= head block =================
    float wlgr[64], wfcr[32], wsk0[32];
    {
      const float4* lb = (const float4*)(Wlg + (size_t)jz * 128 + kh * 64);
#pragma unroll
      for (int m = 0; m < 16; m++) {
        const float4 v = lb[m];
        wlgr[4 * m] = v.x; wlgr[4 * m + 1] = v.y;
        wlgr[4 * m + 2] = v.z; wlgr[4 * m + 3] = v.w;
      }
      const float4* fb = (const float4*)(Wfcw + (size_t)j3 * 128 + q3 * 32);
      const float4* sb = (const float4*)(Wskip0 + (size_t)j3 * 128 + q3 * 32);
#pragma unroll
      for (int m = 0; m < 8; m++) {
        const float4 v = fb[m];
        const float4 u = sb[m];
        wfcr[4 * m] = v.x; wfcr[4 * m + 1] = v.y;
        wfcr[4 * m + 2] = v.z; wfcr[4 * m + 3] = v.w;
        wsk0[4 * m] = u.x; wsk0[4 * m + 1] = u.y;
        wsk0[4 * m + 2] = u.z; wsk0[4 * m + 3] = u.w;
      }
    }
    float wf0 = 0.f, wf1 = 0.f, bfv = 0.f, bs0 = 0.f, bsum = 0.f, bfcv = 0.f;
    if (tid < 128) {
      wf0 = Wfirst[2 * tid]; wf1 = Wfirst[2 * tid + 1]; bfv = bfirst[tid];
      bs0 = bskip0[tid];
      for (int l2 = 0; l2 < 16; l2++) bsum += bskipl[l2 * 128 + tid];
      bfcv = bfc[tid];
      for (int e = 0; e < 4; e++) {
        float a = 0.f;
        for (int c = 0; c < 64; c++)
          a = fmaf(enc[(b * 64 + c) * 4 + e], Wct[tid * 64 + c], a);
        ct2[e * 128 + tid] = a;
      }
    }
    const float blgv = (tid < 256) ? blgg[tid] : 0.f;
    float fq = 0.f, x = 128.f / 127.5f - 1.f;
    u64* res0box = (u64*)(ws + RESBOX_OFF + (size_t)b * BOXB);  // layer-0 inbox
    u64* skb = (u64*)(ws + SKIPBOX_OFF + (size_t)b * BOXB);
    float* res0S = resS;
    float* partS = zpartS;  // [512]
    float* lgS = ppS;       // [512]
    float* skS = hS;        // [128]
    float* s1S = rpartS;    // [128]
    __syncthreads();

    for (int t = 0; t < TSTEPS; t++) {
      const unsigned want = (unsigned)(t + 1);
      const int e = t / CREP;

      // first causal conv; publish res0 immediately (starts the ring)
      if (tid < 128) {
        const float rv = fmaf(fq, wf0, fmaf(x, wf1, bfv));
        pub64(res0box + tid, rv, want);
        res0S[tid] = rv;
      }
      __syncthreads();

      // skip0 partials (VGPR wsk0)
      {
        const float* rp = res0S + q3 * 32;
        float sp = 0.f;
#pragma unroll
        for (int kk = 0; kk < 32; kk++) sp = fmaf(rp[kk], wsk0[kk], sp);
        partS[tid] = sp;  // tid == q3*128 + j3
      }
      __syncthreads();
      if (tid < 128) {
        float sacc = partS[tid] + partS[128 + tid] + partS[256 + tid] + partS[384 + tid] +
                     bs0 + bsum;
        // poll all 16 per-layer skip boxes (4 groups x 4 concurrent atomics)
        u64 v[16];
        int g = 0;
        for (;;) {
          bool ok = true;
#pragma unroll
          for (int grp = 0; grp < 4; grp++)
            poll4(skb + grp * 512 + tid, v[grp * 4], v[grp * 4 + 1], v[grp * 4 + 2],
                  v[grp * 4 + 3]);
#pragma unroll
          for (int l2 = 0; l2 < 16; l2++) ok &= ((unsigned)(v[l2] >> 32) == want);
          if (ok) break;
          if (((++g) & 63) == 0) {
            if (g > (SPIN_LIMIT >> 6) || ld32(abt)) { st32(abt, 1u); break; }
          }
        }
#pragma unroll
        for (int l2 = 0; l2 < 16; l2++) sacc += __uint_as_float((unsigned)v[l2]);
        skS[tid] = fmaxf(sacc, 0.f);
      }
      __syncthreads();

      // s1 partials: relu(skip) @ Wfc
      {
        const float* sp2 = skS + q3 * 32;
        float p = 0.f;
#pragma unroll
        for (int kk = 0; kk < 32; kk++) p = fmaf(sp2[kk], wfcr[kk], p);
        partS[tid] = p;
      }
      __syncthreads();
      if (tid < 128)
        s1S[tid] = fmaxf(partS[tid] + partS[128 + tid] + partS[256 + tid] +
                             partS[384 + tid] + bfcv + ct2[e * 128 + tid],
                         0.f);
      __syncthreads();

      // logit partials: relu(s1) @ Wlogits
      {
        const float* sp3 = s1S + kh * 64;
        float p = 0.f;
#pragma unroll
        for (int kk = 0; kk < 64; kk++) p = fmaf(sp3[kk], wlgr[kk], p);
        lgS[(kh << 8) | jz] = p;
      }
      __syncthreads();

      float lg = 0.f;
      if (tid < 256) lg = lgS[tid] + lgS[256 + tid] + blgv;

      // argmax over 256 classes (tid<256, np first-max tie rule)
      {
        float bv = lg;
        int bi = tid;
#pragma unroll
        for (int off = 32; off >= 1; off >>= 1) {
          const float ov = __shfl_down(bv, (unsigned)off);
          const int oi = __shfl_down(bi, (unsigned)off);
          if (ov > bv || (ov == bv && oi < bi)) { bv = ov; bi = oi; }
        }
        if (tid < 256 && (tid & 63) == 0) { amaxv[tid >> 6] = bv; amaxi[tid >> 6] = bi; }
      }
      __syncthreads();
      if (tid == 0) {
        float bb = amaxv[0];
        int ii = amaxi[0];
        for (int w2 = 1; w2 < 4; w2++)
          if (amaxv[w2] > bb || (amaxv[w2] == bb && amaxi[w2] < ii)) {
            bb = amaxv[w2]; ii = amaxi[w2];
          }
        argixS[0] = ii;
      }
      __syncthreads();
      fq = x;
      x = (float)argixS[0] / 127.5f - 1.f;

      if (tid < 256) dout[((size_t)b * 256 + tid) * TSTEPS + t] = lg;
    }
  }
}

extern "C" void kernel_launch(void* const* d_in, const int* in_sizes, int n_in,
                              void* d_out, int out_size, void* d_ws, size_t ws_size,
                              hipStream_t stream) {
  (void)in_sizes; (void)n_in; (void)out_size; (void)ws_size;
  wn_init<<<256, 256, 0, stream>>>((unsigned char*)d_ws);
  wn_main<<<1024, 512, 0, stream>>>(
      (const float*)d_in[0], (const float*)d_in[1], (const float*)d_in[2],
      (const float*)d_in[3], (const float*)d_in[4], (const float*)d_in[5],
      (const float*)d_in[6], (const float*)d_in[7], (const float*)d_in[8],
      (const float*)d_in[9], (const float*)d_in[10], (const float*)d_in[11],
      (const float*)d_in[12], (const float*)d_in[13], (const float*)d_in[14],
      (const float*)d_in[15], (const float*)d_in[16],
      (float*)d_out, (unsigned char*)d_ws);
}